// Round 9
// baseline (208.590 us; speedup 1.0000x reference)
//
#include <hip/hip_runtime.h>

typedef unsigned int u32;
typedef unsigned long long u64;
typedef _Float16 f16;
typedef f16 half8 __attribute__((ext_vector_type(8)));
typedef float f32x4 __attribute__((ext_vector_type(4)));

// ---------------- threefry2x32-20 (exact JAX replica, partitionable mode) ----
struct U2 { u32 x, y; };

__host__ __device__ constexpr u32 rotl32(u32 v, int r) {
  return (v << r) | (v >> (32 - r));
}

__host__ __device__ constexpr U2 threefry2x32(u32 k0, u32 k1, u32 c0, u32 c1) {
  u32 ks2 = k0 ^ k1 ^ 0x1BD11BDAu;
  u32 x0 = c0 + k0, x1 = c1 + k1;
#define TFR(r) { x0 += x1; x1 = rotl32(x1, r); x1 ^= x0; }
  TFR(13) TFR(15) TFR(26) TFR(6)
  x0 += k1; x1 += ks2 + 1u;
  TFR(17) TFR(29) TFR(16) TFR(24)
  x0 += ks2; x1 += k0 + 2u;
  TFR(13) TFR(15) TFR(26) TFR(6)
  x0 += k0; x1 += k1 + 3u;
  TFR(17) TFR(29) TFR(16) TFR(24)
  x0 += k1; x1 += ks2 + 4u;
  TFR(13) TFR(15) TFR(26) TFR(6)
  x0 += ks2; x1 += k0 + 5u;
#undef TFR
  return {x0, x1};
}

constexpr U2 SK1 = threefry2x32(0u, 42u, 0u, 0u);   // k1 (for g1)
constexpr U2 SK2 = threefry2x32(0u, 42u, 0u, 1u);   // k2 (for g2)
constexpr u32 K1A = SK1.x, K1B = SK1.y;
constexpr u32 K2A = SK2.x, K2B = SK2.y;

#define NACT 47

__device__ __forceinline__ float gumbel_at(u32 kA, u32 kB, u32 i) {
  U2 r = threefry2x32(kA, kB, 0u, i);
  u32 bits = r.x ^ r.y;
  float f = __uint_as_float(0x3f800000u | (bits >> 9)) - 1.0f;
  f = fmaxf(f, 1.17549435e-38f);
  return -logf(-logf(f));
}

// monotone float->u32 map (handles -inf; no NaN in inputs)
__device__ __forceinline__ u32 fmono(float f) {
  u32 b = __float_as_uint(f);
  return b ^ ((b & 0x80000000u) ? 0xFFFFFFFFu : 0x80000000u);
}

// ---------------- d_ws layout (identical to rounds 7/8, proven) -------------
#define W1H_OFF 0u
#define W1_CB   18432u      // per 64k chunk: 128 cols x 144 B (72 f16 slots, 64 used)
#define W1L_OFF 294912u
#define W2H_OFF 589824u
#define W2_CB   10240u      // per 32k chunk: 128 cols x 80 B
#define W2L_OFF 630784u
#define W3H_OFF 671744u
#define W3_CB   8192u       // per 32k chunk: 96 cols x 80 B, padded
#define W3L_OFF 704512u
#define WS_NEEDED 737280u

__global__ __launch_bounds__(256)
void prep_weights(const float* __restrict__ W1, const float* __restrict__ W2,
                  const float* __restrict__ W3, char* __restrict__ ws) {
  const int bid = blockIdx.x, t = threadIdx.x;
  if (bid < 512) {                       // W1: 1024x128
    int idx = bid * 256 + t;
    int c = idx & 127, kA = idx >> 7;
    int cc = kA >> 6, kk = kA & 63;
    float w = W1[(size_t)kA * 128 + c] * 32.0f;
    f16 h = (f16)w;
    f16 l = (f16)((w - (float)h) * 2048.0f);
    *(f16*)(ws + W1H_OFF + cc * W1_CB + c * 144 + 2 * kk) = h;
    *(f16*)(ws + W1L_OFF + cc * W1_CB + c * 144 + 2 * kk) = l;
  } else if (bid < 576) {                // W2: 128x128
    int idx = (bid - 512) * 256 + t;
    int c = idx & 127, kA = idx >> 7;
    int cc = kA >> 5, kk = kA & 31;
    float w = W2[(size_t)kA * 128 + c] * 32.0f;
    f16 h = (f16)w;
    f16 l = (f16)((w - (float)h) * 2048.0f);
    *(f16*)(ws + W2H_OFF + cc * W2_CB + c * 80 + 2 * kk) = h;
    *(f16*)(ws + W2L_OFF + cc * W2_CB + c * 80 + 2 * kk) = l;
  } else {                               // W3: 128x94 -> padded 96 cols
    int idx = (bid - 576) * 256 + t;     // 48 blocks * 256 = 12288 = 128*96
    int c = idx % 96, kA = idx / 96;
    int cc = kA >> 5, kk = kA & 31;
    float w = (c < 94) ? W3[(size_t)kA * 94 + c] * 32.0f : 0.0f;
    f16 h = (f16)w;
    f16 l = (f16)((w - (float)h) * 2048.0f);
    *(f16*)(ws + W3H_OFF + cc * W3_CB + c * 80 + 2 * kk) = h;
    *(f16*)(ws + W3L_OFF + cc * W3_CB + c * 80 + 2 * kk) = l;
  }
}

__device__ __forceinline__ void gl_lds16(const void* g, void* l) {
  __builtin_amdgcn_global_load_lds(
      (const __attribute__((address_space(1))) unsigned int*)g,
      (__attribute__((address_space(3))) unsigned int*)l, 16, 0, 0);
}

__device__ __forceinline__ f32x4 mfma16(half8 a, half8 b, f32x4 c) {
  return __builtin_amdgcn_mfma_f32_16x16x32_f16(a, b, c, 0, 0, 0);
}

__device__ __forceinline__ void split8(float4 v0, float4 v1, half8& hi, half8& lo) {
  float xs[8] = {v0.x, v0.y, v0.z, v0.w, v1.x, v1.y, v1.z, v1.w};
#pragma unroll
  for (int i = 0; i < 8; i++) {
    f16 h = (f16)xs[i];
    hi[i] = h;
    lo[i] = (f16)((xs[i] - (float)h) * 2048.0f);
  }
}

#define SB() __builtin_amdgcn_sched_barrier(0)
// counted-vmcnt barrier: stage(+loadx) issued this phase stay in flight
#define BAR_VM17() asm volatile("s_waitcnt vmcnt(17)\n\ts_barrier" ::: "memory")
#define BAR_VM0()  asm volatile("s_waitcnt vmcnt(0)\n\ts_barrier" ::: "memory")
#define BAR_LGKM() asm volatile("s_waitcnt lgkmcnt(0)\n\ts_barrier" ::: "memory")

// ---------------- pipelined MFMA fused policy kernel ----------------
// 64 rows/block, 256 threads = 4 waves in 2x2 (wr rows, wc cols).
// LDS arena 74752 B:
//  L1: Wbuf0 [0,36864) {hi,lo}, Wbuf1 [36864,73728)
//  L2: Hb f32[64][132] [0,33792); W2 bufs at 33792 + {0,20480}
//  L3: Hb;                W3 bufs at 33792 + {0,16384}
//  S : Ls f32[64][97] [0,24832); action mask read direct from global
__global__ __launch_bounds__(256)
void fused_mfma(const float* __restrict__ X, const int* __restrict__ AM,
                const float* __restrict__ b1, const float* __restrict__ b2,
                const float* __restrict__ b3, const char* __restrict__ ws,
                int* __restrict__ out) {
  __shared__ __align__(16) char smem[74752];
  const int t = threadIdx.x;
  const int lane = t & 63, wid = t >> 6;
  const int lrow = lane & 15, g = lane >> 4;
  const int wr = wid & 1, wc = wid >> 1;
  const int rowBase = blockIdx.x * 64;

  f32x4 mainA[2][4], crossA[2][4], accF[2][4];
#pragma unroll
  for (int ti = 0; ti < 2; ti++)
#pragma unroll
    for (int tc = 0; tc < 4; tc++)
#pragma unroll
      for (int r = 0; r < 4; r++) {
        mainA[ti][tc][r] = 0.0f; crossA[ti][tc][r] = 0.0f; accF[ti][tc][r] = 0.0f;
      }

  // stage_w1: EXACTLY 9 gl_lds per wave (uniform -> exact vmcnt accounting)
  auto stage_w1 = [&](int cc, int bufoff) {
    for (int i = wid; i < 36; i += 4) {           // 9 iters per wave
      int sel = i & 1, is = i >> 1;
      gl_lds16(ws + (sel ? W1L_OFF : W1H_OFF) + (u32)cc * W1_CB + is * 1024 + lane * 16,
               smem + bufoff + sel * 18432 + is * 1024);
    }
  };
  auto stage_w2 = [&](int cc, int bufoff) {
    for (int is = wid; is < 10; is += 4) {
      gl_lds16(ws + W2H_OFF + (u32)cc * W2_CB + is * 1024 + lane * 16,
               smem + bufoff + is * 1024);
      gl_lds16(ws + W2L_OFF + (u32)cc * W2_CB + is * 1024 + lane * 16,
               smem + bufoff + 10240 + is * 1024);
    }
  };
  auto stage_w3 = [&](int cc, int bufoff) {
    for (int is = wid; is < 8; is += 4) {
      gl_lds16(ws + W3H_OFF + (u32)cc * W3_CB + is * 1024 + lane * 16,
               smem + bufoff + is * 1024);
      gl_lds16(ws + W3L_OFF + (u32)cc * W3_CB + is * 1024 + lane * 16,
               smem + bufoff + 8192 + is * 1024);
    }
  };
  auto loadx = [&](int c, float4* xr) {            // exactly 8 dwordx4 per lane
#pragma unroll
    for (int ti = 0; ti < 2; ti++) {
      const float* xp = X + (size_t)(rowBase + 32 * wr + 16 * ti + lrow) * 1024
                          + c * 64 + 8 * g;
#pragma unroll
      for (int ks = 0; ks < 2; ks++) {
        xr[ti * 4 + ks * 2 + 0] = *(const float4*)(xp + ks * 32);
        xr[ti * 4 + ks * 2 + 1] = *(const float4*)(xp + ks * 32 + 4);
      }
    }
  };
  auto compute_w1 = [&](const float4* xr, int bufoff) {
#pragma unroll
    for (int ks = 0; ks < 2; ks++) {
      half8 ah[2], al[2];
#pragma unroll
      for (int ti = 0; ti < 2; ti++)
        split8(xr[ti * 4 + ks * 2], xr[ti * 4 + ks * 2 + 1], ah[ti], al[ti]);
#pragma unroll
      for (int tc = 0; tc < 4; tc++) {
        const int col = 64 * wc + 16 * tc + lrow;
        half8 bh = *(const half8*)(smem + bufoff + col * 144 + 2 * (ks * 32 + 8 * g));
        half8 bl = *(const half8*)(smem + bufoff + 18432 + col * 144 + 2 * (ks * 32 + 8 * g));
#pragma unroll
        for (int ti = 0; ti < 2; ti++) {
          mainA[ti][tc]  = mfma16(ah[ti], bh, mainA[ti][tc]);
          crossA[ti][tc] = mfma16(ah[ti], bl, crossA[ti][tc]);
          crossA[ti][tc] = mfma16(al[ti], bh, crossA[ti][tc]);
        }
      }
    }
  };
  auto fold = [&]() {
#pragma unroll
    for (int ti = 0; ti < 2; ti++)
#pragma unroll
      for (int tc = 0; tc < 4; tc++)
#pragma unroll
        for (int r = 0; r < 4; r++) {
          accF[ti][tc][r] += mainA[ti][tc][r] + crossA[ti][tc][r] * 4.8828125e-4f;
          mainA[ti][tc][r] = 0.0f; crossA[ti][tc][r] = 0.0f;
        }
  };

  // ===== layer 1: h1 = relu(X @ W1 + b1), K=1024, counted-vmcnt pipeline ====
  float4 xA[8], xB[8];
  // prologue: 2-deep prefetch
  stage_w1(0, 0);        SB();
  loadx(0, xA);          SB();
  stage_w1(1, 36864);    SB();
  loadx(1, xB);          SB();
  BAR_VM17();            // stage(0)+loadx(0) done; stage(1)+loadx(1) in flight
  SB();

  for (int c = 0; c < 16; c += 2) {
    // ---- phase A: compute chunk c from buf0/xA ----
    compute_w1(xA, 0);
    fold();
    BAR_LGKM();                         // all waves done reading buf0
    if (c + 2 < 16) {
      stage_w1(c + 2, 0); SB();         // 9 gl_lds
      loadx(c + 2, xA);   SB();         // 8 loads
      BAR_VM17();                       // stage(c+1)+loadx(c+1) done; new 17 fly
    } else {
      BAR_VM0();                        // tail: drain for final chunk
    }
    SB();
    // ---- phase B: compute chunk c+1 from buf1/xB ----
    compute_w1(xB, 36864);
    fold();
    BAR_LGKM();
    if (c + 3 < 16) {
      stage_w1(c + 3, 36864); SB();
      loadx(c + 3, xB);       SB();
      BAR_VM17();
    } else {
      BAR_VM0();
    }
    SB();
  }

  // h1 epilogue -> Hb [0,33792) stride 132; kick W2 chunk 0 (disjoint region)
  float* Hb = (float*)smem;
  stage_w2(0, 33792);
  {
    const float bb[4] = {b1[64 * wc + 16 * 0 + lrow], b1[64 * wc + 16 * 1 + lrow],
                         b1[64 * wc + 16 * 2 + lrow], b1[64 * wc + 16 * 3 + lrow]};
#pragma unroll
    for (int ti = 0; ti < 2; ti++)
#pragma unroll
      for (int tc = 0; tc < 4; tc++) {
        const int col = 64 * wc + 16 * tc + lrow;
#pragma unroll
        for (int r = 0; r < 4; r++) {
          const int row = 32 * wr + 16 * ti + 4 * g + r;
          Hb[row * 132 + col] = fmaxf(accF[ti][tc][r] * 0.03125f + bb[tc], 0.0f);
          accF[ti][tc][r] = 0.0f;
        }
      }
  }
  __syncthreads();

  // ===== layer 2: h2 = relu(h1 @ W2 + b2), K=128 =====
  for (int cc = 0; cc < 4; cc++) {
    const int cur = 33792 + (cc & 1) * 20480;
    if (cc < 3) stage_w2(cc + 1, 33792 + ((cc + 1) & 1) * 20480);
    else        stage_w3(0, 33792);   // W2 buf0 dead; chain W3 chunk 0
    half8 ah[2], al[2];
#pragma unroll
    for (int ti = 0; ti < 2; ti++) {
      const float* hp = Hb + (32 * wr + 16 * ti + lrow) * 132 + cc * 32 + 8 * g;
      split8(*(const float4*)hp, *(const float4*)(hp + 4), ah[ti], al[ti]);
    }
#pragma unroll
    for (int tc = 0; tc < 4; tc++) {
      const int col = 64 * wc + 16 * tc + lrow;
      half8 bh = *(const half8*)(smem + cur + col * 80 + 16 * g);
      half8 bl = *(const half8*)(smem + cur + 10240 + col * 80 + 16 * g);
#pragma unroll
      for (int ti = 0; ti < 2; ti++) {
        mainA[ti][tc]  = mfma16(ah[ti], bh, mainA[ti][tc]);
        crossA[ti][tc] = mfma16(ah[ti], bl, crossA[ti][tc]);
        crossA[ti][tc] = mfma16(al[ti], bh, crossA[ti][tc]);
      }
    }
    fold();
    __syncthreads();
  }
  // h2 epilogue (overlays h1)
  {
    const float bb[4] = {b2[64 * wc + 16 * 0 + lrow], b2[64 * wc + 16 * 1 + lrow],
                         b2[64 * wc + 16 * 2 + lrow], b2[64 * wc + 16 * 3 + lrow]};
#pragma unroll
    for (int ti = 0; ti < 2; ti++)
#pragma unroll
      for (int tc = 0; tc < 4; tc++) {
        const int col = 64 * wc + 16 * tc + lrow;
#pragma unroll
        for (int r = 0; r < 4; r++) {
          const int row = 32 * wr + 16 * ti + 4 * g + r;
          Hb[row * 132 + col] = fmaxf(accF[ti][tc][r] * 0.03125f + bb[tc], 0.0f);
          accF[ti][tc][r] = 0.0f;
        }
      }
  }
  __syncthreads();

  // ===== layer 3: logits = h2 @ W3 + b3, 96 (94) cols =====
  f32x4 main3[2][3], cross3[2][3], accF3[2][3];
#pragma unroll
  for (int ti = 0; ti < 2; ti++)
#pragma unroll
    for (int tc = 0; tc < 3; tc++)
#pragma unroll
      for (int r = 0; r < 4; r++) {
        main3[ti][tc][r] = 0.0f; cross3[ti][tc][r] = 0.0f; accF3[ti][tc][r] = 0.0f;
      }
  for (int cc = 0; cc < 4; cc++) {
    const int cur = 33792 + (cc & 1) * 16384;
    if (cc < 3) stage_w3(cc + 1, 33792 + ((cc + 1) & 1) * 16384);
    half8 ah[2], al[2];
#pragma unroll
    for (int ti = 0; ti < 2; ti++) {
      const float* hp = Hb + (32 * wr + 16 * ti + lrow) * 132 + cc * 32 + 8 * g;
      split8(*(const float4*)hp, *(const float4*)(hp + 4), ah[ti], al[ti]);
    }
#pragma unroll
    for (int tc = 0; tc < 3; tc++) {
      const int col = 48 * wc + 16 * tc + lrow;
      half8 bh = *(const half8*)(smem + cur + col * 80 + 16 * g);
      half8 bl = *(const half8*)(smem + cur + 8192 + col * 80 + 16 * g);
#pragma unroll
      for (int ti = 0; ti < 2; ti++) {
        main3[ti][tc]  = mfma16(ah[ti], bh, main3[ti][tc]);
        cross3[ti][tc] = mfma16(ah[ti], bl, cross3[ti][tc]);
        cross3[ti][tc] = mfma16(al[ti], bh, cross3[ti][tc]);
      }
    }
#pragma unroll
    for (int ti = 0; ti < 2; ti++)
#pragma unroll
      for (int tc = 0; tc < 3; tc++)
#pragma unroll
        for (int r = 0; r < 4; r++) {
          accF3[ti][tc][r] += main3[ti][tc][r] + cross3[ti][tc][r] * 4.8828125e-4f;
          main3[ti][tc][r] = 0.0f; cross3[ti][tc][r] = 0.0f;
        }
    __syncthreads();
  }

  // logits epilogue -> Ls (overlays Hb)
  float* Ls = (float*)smem;                 // [64][97]
#pragma unroll
  for (int ti = 0; ti < 2; ti++)
#pragma unroll
    for (int tc = 0; tc < 3; tc++) {
      const int col = 48 * wc + 16 * tc + lrow;
      const float bb = (col < 94) ? b3[col] : 0.0f;
#pragma unroll
      for (int r = 0; r < 4; r++) {
        const int row = 32 * wr + 16 * ti + 4 * g + r;
        Ls[row * 97 + col] = accF3[ti][tc][r] * 0.03125f + bb;
      }
    }
  __syncthreads();

  // ===== sampling: 4 lanes per row, mask direct from global =====
  {
    const int row = 16 * wid + lrow;        // 0..63
    const int q = g;                        // 0..3
    const int* amg = AM + (size_t)(rowBase + row) * 94;
    const float* ls = Ls + row * 97;
    const float NI = -__builtin_huge_valf();

    int amv1[12], amv2[12];
    int s0 = 0, s1 = 0;
#pragma unroll
    for (int k = 0; k < 12; k++) {
      const int a = q + 4 * k;
      amv1[k] = (a < NACT) ? amg[a] : 0;
      amv2[k] = (a < NACT) ? amg[NACT + a] : 0;
      s0 += amv1[k]; s1 += amv2[k];
    }
    s0 += __shfl_xor(s0, 16); s0 += __shfl_xor(s0, 32);
    s1 += __shfl_xor(s1, 16); s1 += __shfl_xor(s1, 32);
    const int am0 = amg[0], amN = amg[NACT];
    const bool fp1 = (s0 == 1) && (am0 == 1);
    const bool fp2 = (s1 == 1) && (amN == 1);
    const u32 growA = (u32)(rowBase + row) * 47u;

    u64 best = 0;
#pragma unroll
    for (int k = 0; k < 12; k++) {
      const int a = q + 4 * k;
      if (a >= NACT) break;
      float l = (amv1[k] != 0) ? ls[a] : NI;
      if (fp2 && !fp1 && a == 0) l = NI;
      float v = l + gumbel_at(K1A, K1B, growA + (u32)a);
      u64 key = ((u64)fmono(v) << 6) | (u32)(63 - a);
      if (key > best) best = key;
    }
    u64 o = __shfl_xor(best, 16); if (o > best) best = o;
    o = __shfl_xor(best, 32); if (o > best) best = o;
    const int a1 = fp1 ? 0 : (63 - (int)(best & 63u));

    const bool sw1 = (a1 >= 1) && (a1 <= 6);
    const bool mv1 = (a1 >= 27);
    best = 0;
#pragma unroll
    for (int k = 0; k < 12; k++) {
      const int a = q + 4 * k;
      if (a >= NACT) break;
      float l = (amv2[k] != 0) ? ls[NACT + a] : NI;
      bool extra = (sw1 && a == a1) || (mv1 && a >= 27 && a < 46);
      if ((fp1 && !fp2 && a == 0) || (!fp1 && !fp2 && extra)) l = NI;
      float v = l + gumbel_at(K2A, K2B, growA + (u32)a);
      u64 key = ((u64)fmono(v) << 6) | (u32)(63 - a);
      if (key > best) best = key;
    }
    o = __shfl_xor(best, 16); if (o > best) best = o;
    o = __shfl_xor(best, 32); if (o > best) best = o;
    const int a2 = fp2 ? 0 : (63 - (int)(best & 63u));

    if (q == 0) {
      out[(size_t)(rowBase + row) * 2 + 0] = a1;
      out[(size_t)(rowBase + row) * 2 + 1] = a2;
    }
  }
}

// ---------------- fallback: round-6 proven f32 kernel (used if ws too small)
__global__ __launch_bounds__(256)
void fused_policy_v1(const float* __restrict__ X,  const int* __restrict__ AM,
                     const float* __restrict__ W1, const float* __restrict__ b1,
                     const float* __restrict__ W2, const float* __restrict__ b2,
                     const float* __restrict__ W3, const float* __restrict__ b3,
                     int* __restrict__ out) {
  __shared__ alignas(16) char smem[59904];
  float (*HT)[68]   = reinterpret_cast<float (*)[68]>(smem);
  float (*Wst)[128] = reinterpret_cast<float (*)[128]>(smem + 34816);
  float (*Ws3)[96]  = reinterpret_cast<float (*)[96]>(smem + 34816);
  float (*Xt)[68]   = reinterpret_cast<float (*)[68]>(smem + 51200);
  float (*Lsr)[97]  = reinterpret_cast<float (*)[97]>(smem);
  int*   Amf        = reinterpret_cast<int*>(smem + 34816);

  const int t = threadIdx.x;
  const int rowBase = blockIdx.x * 64;
  const int tx = t & 31, ty = t >> 5;
  const int c0 = tx * 4, r0 = ty * 8;

  float accf[8][4]; double accd[8][4];
#pragma unroll
  for (int i = 0; i < 8; i++)
#pragma unroll
    for (int j = 0; j < 4; j++) { accf[i][j] = 0.0f; accd[i][j] = 0.0; }

  for (int k0 = 0; k0 < 1024; k0 += 32) {
#pragma unroll
    for (int i = 0; i < 2; i++) {
      int idx = t + i * 256;
      int row = idx >> 3, kb = (idx & 7) * 4;
      float4 v = *reinterpret_cast<const float4*>(X + (size_t)(rowBase + row) * 1024 + k0 + kb);
      Xt[kb + 0][row] = v.x; Xt[kb + 1][row] = v.y;
      Xt[kb + 2][row] = v.z; Xt[kb + 3][row] = v.w;
    }
#pragma unroll
    for (int i = 0; i < 4; i++) {
      int idx = t + i * 256;
      int kr = idx >> 5, c4 = (idx & 31) * 4;
      *reinterpret_cast<float4*>(&Wst[kr][c4]) =
          *reinterpret_cast<const float4*>(W1 + (size_t)(k0 + kr) * 128 + c4);
    }
    __syncthreads();
#pragma unroll
    for (int kk = 0; kk < 32; kk++) {
      float4 a0 = *reinterpret_cast<const float4*>(&Xt[kk][r0]);
      float4 a1 = *reinterpret_cast<const float4*>(&Xt[kk][r0 + 4]);
      float4 b  = *reinterpret_cast<const float4*>(&Wst[kk][c0]);
      float av[8] = {a0.x, a0.y, a0.z, a0.w, a1.x, a1.y, a1.z, a1.w};
      float bv[4] = {b.x, b.y, b.z, b.w};
#pragma unroll
      for (int i = 0; i < 8; i++)
#pragma unroll
        for (int j = 0; j < 4; j++) accf[i][j] = fmaf(av[i], bv[j], accf[i][j]);
    }
    if ((k0 & 63) == 32) {
#pragma unroll
      for (int i = 0; i < 8; i++)
#pragma unroll
        for (int j = 0; j < 4; j++) { accd[i][j] += (double)accf[i][j]; accf[i][j] = 0.0f; }
    }
    __syncthreads();
  }
  {
    const float4 bv = *reinterpret_cast<const float4*>(b1 + c0);
#pragma unroll
    for (int i = 0; i < 8; i++) {
      HT[c0 + 0][r0 + i] = fmaxf((float)accd[i][0] + bv.x, 0.0f);
      HT[c0 + 1][r0 + i] = fmaxf((float)accd[i][1] + bv.y, 0.0f);
      HT[c0 + 2][r0 + i] = fmaxf((float)accd[i][2] + bv.z, 0.0f);
      HT[c0 + 3][r0 + i] = fmaxf((float)accd[i][3] + bv.w, 0.0f);
    }
  }
  __syncthreads();

#pragma unroll
  for (int i = 0; i < 8; i++)
#pragma unroll
    for (int j = 0; j < 4; j++) { accf[i][j] = 0.0f; accd[i][j] = 0.0; }
  for (int k0 = 0; k0 < 128; k0 += 32) {
#pragma unroll
    for (int i = 0; i < 4; i++) {
      int idx = t + i * 256;
      int kr = idx >> 5, c4 = (idx & 31) * 4;
      *reinterpret_cast<float4*>(&Wst[kr][c4]) =
          *reinterpret_cast<const float4*>(W2 + (size_t)(k0 + kr) * 128 + c4);
    }
    __syncthreads();
#pragma unroll
    for (int kk = 0; kk < 32; kk++) {
      float4 a0 = *reinterpret_cast<const float4*>(&HT[k0 + kk][r0]);
      float4 a1 = *reinterpret_cast<const float4*>(&HT[k0 + kk][r0 + 4]);
      float4 b  = *reinterpret_cast<const float4*>(&Wst[kk][c0]);
      float av[8] = {a0.x, a0.y, a0.z, a0.w, a1.x, a1.y, a1.z, a1.w};
      float bv[4] = {b.x, b.y, b.z, b.w};
#pragma unroll
      for (int i = 0; i < 8; i++)
#pragma unroll
        for (int j = 0; j < 4; j++) accf[i][j] = fmaf(av[i], bv[j], accf[i][j]);
    }
    if ((k0 & 63) == 32) {
#pragma unroll
      for (int i = 0; i < 8; i++)
#pragma unroll
        for (int j = 0; j < 4; j++) { accd[i][j] += (double)accf[i][j]; accf[i][j] = 0.0f; }
    }
    __syncthreads();
  }
  {
    const float4 bv = *reinterpret_cast<const float4*>(b2 + c0);
#pragma unroll
    for (int i = 0; i < 8; i++) {
      HT[c0 + 0][r0 + i] = fmaxf((float)accd[i][0] + bv.x, 0.0f);
      HT[c0 + 1][r0 + i] = fmaxf((float)accd[i][1] + bv.y, 0.0f);
      HT[c0 + 2][r0 + i] = fmaxf((float)accd[i][2] + bv.z, 0.0f);
      HT[c0 + 3][r0 + i] = fmaxf((float)accd[i][3] + bv.w, 0.0f);
    }
  }
  __syncthreads();

  const int c3 = tx * 3;
  float acc3f[8][3]; double acc3d[8][3];
#pragma unroll
  for (int i = 0; i < 8; i++)
#pragma unroll
    for (int j = 0; j < 3; j++) { acc3f[i][j] = 0.0f; acc3d[i][j] = 0.0; }
  for (int k0 = 0; k0 < 128; k0 += 32) {
#pragma unroll
    for (int i = 0; i < 12; i++) {
      int idx = t + i * 256;
      int kr = idx / 96, c = idx - kr * 96;
      Ws3[kr][c] = (c < 94) ? W3[(size_t)(k0 + kr) * 94 + c] : 0.0f;
    }
    __syncthreads();
#pragma unroll
    for (int kk = 0; kk < 32; kk++) {
      float4 a0 = *reinterpret_cast<const float4*>(&HT[k0 + kk][r0]);
      float4 a1 = *reinterpret_cast<const float4*>(&HT[k0 + kk][r0 + 4]);
      float b0 = Ws3[kk][c3], b1v = Ws3[kk][c3 + 1], b2v = Ws3[kk][c3 + 2];
      float av[8] = {a0.x, a0.y, a0.z, a0.w, a1.x, a1.y, a1.z, a1.w};
      float bv3[3] = {b0, b1v, b2v};
#pragma unroll
      for (int i = 0; i < 8; i++)
#pragma unroll
        for (int j = 0; j < 3; j++) acc3f[i][j] = fmaf(av[i], bv3[j], acc3f[i][j]);
    }
    if ((k0 & 63) == 32) {
#pragma unroll
      for (int i = 0; i < 8; i++)
#pragma unroll
        for (int j = 0; j < 3; j++) { acc3d[i][j] += (double)acc3f[i][j]; acc3f[i][j] = 0.0f; }
    }
    __syncthreads();
  }
  {
    float b3v[3];
#pragma unroll
    for (int j = 0; j < 3; j++) b3v[j] = (c3 + j < 94) ? b3[c3 + j] : 0.0f;
#pragma unroll
    for (int i = 0; i < 8; i++)
#pragma unroll
      for (int j = 0; j < 3; j++)
        Lsr[r0 + i][c3 + j] = (float)acc3d[i][j] + b3v[j];
  }
#pragma unroll
  for (int i = 0; i < 24; i++) {
    int idx = t + i * 256;
    if (idx < 64 * 94) Amf[idx] = AM[(size_t)rowBase * 94 + idx];
  }
  __syncthreads();

  if (t < 64) {
    const int row = rowBase + t;
    const float NI = -__builtin_huge_valf();
    const int* am = Amf + t * 94;
    int sum0 = 0, sum1 = 0;
    for (int a = 0; a < NACT; a++) { sum0 += am[a]; sum1 += am[NACT + a]; }
    const bool fp1 = (sum0 == 1) && (am[0] == 1);
    const bool fp2 = (sum1 == 1) && (am[NACT] == 1);
    float bestv = NI; int a1s = 0;
    for (int a = 0; a < NACT; a++) {
      float l = (am[a] != 0) ? Lsr[t][a] : NI;
      if (fp2 && !fp1 && a == 0) l = NI;
      float v = l + gumbel_at(K1A, K1B, (u32)row * 47u + (u32)a);
      if (v > bestv) { bestv = v; a1s = a; }
    }
    const int a1 = fp1 ? 0 : a1s;
    const bool sw1 = (a1 >= 1) && (a1 <= 6);
    const bool mv1 = (a1 >= 27) && (a1 <= 46);
    bestv = NI; int a2s = 0;
    for (int a = 0; a < NACT; a++) {
      float l = (am[NACT + a] != 0) ? Lsr[t][NACT + a] : NI;
      bool extra = (sw1 && a == a1) || (mv1 && a >= 27 && a < 46);
      bool m2 = (fp1 && !fp2 && a == 0) || (!fp1 && !fp2 && extra);
      if (m2) l = NI;
      float v = l + gumbel_at(K2A, K2B, (u32)row * 47u + (u32)a);
      if (v > bestv) { bestv = v; a2s = a; }
    }
    const int a2 = fp2 ? 0 : a2s;
    out[(size_t)row * 2 + 0] = a1;
    out[(size_t)row * 2 + 1] = a2;
  }
}

extern "C" void kernel_launch(void* const* d_in, const int* in_sizes, int n_in,
                              void* d_out, int out_size, void* d_ws, size_t ws_size,
                              hipStream_t stream) {
  const float* X  = (const float*)d_in[0];
  const int*   AM = (const int*)d_in[1];
  const float* W1 = (const float*)d_in[2];
  const float* b1 = (const float*)d_in[3];
  const float* W2 = (const float*)d_in[4];
  const float* b2 = (const float*)d_in[5];
  const float* W3 = (const float*)d_in[6];
  const float* b3 = (const float*)d_in[7];
  int* out = (int*)d_out;

  if (ws_size >= (size_t)WS_NEEDED) {
    prep_weights<<<624, 256, 0, stream>>>(W1, W2, W3, (char*)d_ws);
    fused_mfma<<<1024, 256, 0, stream>>>(X, AM, b1, b2, b3, (const char*)d_ws, out);
  } else {
    fused_policy_v1<<<1024, 256, 0, stream>>>(X, AM, W1, b1, W2, b2, W3, b3, out);
  }
}

// Round 10
// 151.157 us; speedup vs baseline: 1.3800x; 1.3800x over previous
//
#include <hip/hip_runtime.h>

typedef unsigned int u32;
typedef unsigned long long u64;
typedef _Float16 f16;
typedef f16 half8 __attribute__((ext_vector_type(8)));
typedef float f32x4 __attribute__((ext_vector_type(4)));

// ---------------- threefry2x32-20 (exact JAX replica, partitionable mode) ----
struct U2 { u32 x, y; };

__host__ __device__ constexpr u32 rotl32(u32 v, int r) {
  return (v << r) | (v >> (32 - r));
}

__host__ __device__ constexpr U2 threefry2x32(u32 k0, u32 k1, u32 c0, u32 c1) {
  u32 ks2 = k0 ^ k1 ^ 0x1BD11BDAu;
  u32 x0 = c0 + k0, x1 = c1 + k1;
#define TFR(r) { x0 += x1; x1 = rotl32(x1, r); x1 ^= x0; }
  TFR(13) TFR(15) TFR(26) TFR(6)
  x0 += k1; x1 += ks2 + 1u;
  TFR(17) TFR(29) TFR(16) TFR(24)
  x0 += ks2; x1 += k0 + 2u;
  TFR(13) TFR(15) TFR(26) TFR(6)
  x0 += k0; x1 += k1 + 3u;
  TFR(17) TFR(29) TFR(16) TFR(24)
  x0 += k1; x1 += ks2 + 4u;
  TFR(13) TFR(15) TFR(26) TFR(6)
  x0 += ks2; x1 += k0 + 5u;
#undef TFR
  return {x0, x1};
}

constexpr U2 SK1 = threefry2x32(0u, 42u, 0u, 0u);   // k1 (for g1)
constexpr U2 SK2 = threefry2x32(0u, 42u, 0u, 1u);   // k2 (for g2)
constexpr u32 K1A = SK1.x, K1B = SK1.y;
constexpr u32 K2A = SK2.x, K2B = SK2.y;

#define NACT 47

__device__ __forceinline__ float gumbel_at(u32 kA, u32 kB, u32 i) {
  U2 r = threefry2x32(kA, kB, 0u, i);
  u32 bits = r.x ^ r.y;
  float f = __uint_as_float(0x3f800000u | (bits >> 9)) - 1.0f;
  f = fmaxf(f, 1.17549435e-38f);
  return -logf(-logf(f));
}

// monotone float->u32 map (handles -inf; no NaN in inputs)
__device__ __forceinline__ u32 fmono(float f) {
  u32 b = __float_as_uint(f);
  return b ^ ((b & 0x80000000u) ? 0xFFFFFFFFu : 0x80000000u);
}

// ---------------- d_ws layout: fragment-unit-major split weights ------------
// Each "unit" = 16 cols x 16B (8 f16 at k-consecutive) = 256 B, the exact 16
// lanes x 16B a quarter-wave reads for one MFMA B-fragment. Units ordered so
// a wave's 4 g-groups read 1 KB contiguous. hi = f16(32w), lo = f16((32w-hi)*2048).
#define W1H_OFF 0u          // 16 chunks x 16384 B  (chunk = 64k x 128c)
#define W1L_OFF 262144u
#define W2H_OFF 524288u     // 4 chunks x 8192 B    (chunk = 32k x 128c)
#define W2L_OFF 557056u
#define W3H_OFF 589824u     // 4 chunks x 6144 B    (chunk = 32k x 96c)
#define W3L_OFF 614400u
#define WS_NEEDED 638976u

__global__ __launch_bounds__(256)
void prep_weights(const float* __restrict__ W1, const float* __restrict__ W2,
                  const float* __restrict__ W3, char* __restrict__ ws) {
  const int bid = blockIdx.x, t = threadIdx.x;
  if (bid < 512) {                       // W1: 1024x128
    int idx = bid * 256 + t;
    int col = idx & 127, k = idx >> 7;
    float w = W1[(size_t)k * 128 + col] * 32.0f;
    f16 h = (f16)w;
    f16 l = (f16)((w - (float)h) * 2048.0f);
    u32 addr = (u32)(k >> 6) * 16384u + (u32)(col >> 4) * 2048u +
               (u32)((k >> 5) & 1) * 1024u + (u32)((k >> 3) & 3) * 256u +
               (u32)(col & 15) * 16u + (u32)(k & 7) * 2u;
    *(f16*)(ws + W1H_OFF + addr) = h;
    *(f16*)(ws + W1L_OFF + addr) = l;
  } else if (bid < 576) {                // W2: 128x128
    int idx = (bid - 512) * 256 + t;
    int col = idx & 127, k = idx >> 7;
    float w = W2[(size_t)k * 128 + col] * 32.0f;
    f16 h = (f16)w;
    f16 l = (f16)((w - (float)h) * 2048.0f);
    u32 addr = (u32)(k >> 5) * 8192u + (u32)(col >> 4) * 1024u +
               (u32)((k >> 3) & 3) * 256u + (u32)(col & 15) * 16u + (u32)(k & 7) * 2u;
    *(f16*)(ws + W2H_OFF + addr) = h;
    *(f16*)(ws + W2L_OFF + addr) = l;
  } else {                               // W3: 128x94 -> padded 96 cols
    int idx = (bid - 576) * 256 + t;     // 48 blocks * 256 = 12288 = 128*96
    int col = idx % 96, k = idx / 96;
    float w = (col < 94) ? W3[(size_t)k * 94 + col] * 32.0f : 0.0f;
    f16 h = (f16)w;
    f16 l = (f16)((w - (float)h) * 2048.0f);
    u32 addr = (u32)(k >> 5) * 6144u + (u32)(col >> 4) * 1024u +
               (u32)((k >> 3) & 3) * 256u + (u32)(col & 15) * 16u + (u32)(k & 7) * 2u;
    *(f16*)(ws + W3H_OFF + addr) = h;
    *(f16*)(ws + W3L_OFF + addr) = l;
  }
}

__device__ __forceinline__ f32x4 mfma16(half8 a, half8 b, f32x4 c) {
  return __builtin_amdgcn_mfma_f32_16x16x32_f16(a, b, c, 0, 0, 0);
}

__device__ __forceinline__ void split8(float4 v0, float4 v1, half8& hi, half8& lo) {
  float xs[8] = {v0.x, v0.y, v0.z, v0.w, v1.x, v1.y, v1.z, v1.w};
#pragma unroll
  for (int i = 0; i < 8; i++) {
    f16 h = (f16)xs[i];
    hi[i] = h;
    lo[i] = (f16)((xs[i] - (float)h) * 2048.0f);
  }
}

// ---------------- barrier-light MFMA fused policy kernel ----------------
// 64 rows/block, 256 threads = 4 waves in 2x2 (wr rows, wc cols). 4 blocks/CU.
// L1 is pure dataflow: X global->reg->split; W global(L2)->reg fragments; MFMA
// f32 accumulation across all K (no folds). LDS only for Hb[64][132] (33.8 KB)
// and later Ls[64][97]. 5 barriers total.
__global__ __launch_bounds__(256, 4)
void fused_mfma(const float* __restrict__ X, const int* __restrict__ AM,
                const float* __restrict__ b1, const float* __restrict__ b2,
                const float* __restrict__ b3, const char* __restrict__ ws,
                int* __restrict__ out) {
  __shared__ __align__(16) char smem[33792];     // Hb f32[64][132] / Ls f32[64][97]
  const int t = threadIdx.x;
  const int lane = t & 63, wid = t >> 6;
  const int lrow = lane & 15, g = lane >> 4;
  const int wr = wid & 1, wc = wid >> 1;
  const int rowBase = blockIdx.x * 64;
  float* Hb = (float*)smem;

  f32x4 mainA[2][4], crossA[2][4];
#pragma unroll
  for (int ti = 0; ti < 2; ti++)
#pragma unroll
    for (int tc = 0; tc < 4; tc++)
#pragma unroll
      for (int r = 0; r < 4; r++) { mainA[ti][tc][r] = 0.0f; crossA[ti][tc][r] = 0.0f; }

  // ===== layer 1: h1 = relu(X @ W1 + b1), K=1024, no LDS, no barriers ======
  {
    const float* xb0 = X + (size_t)(rowBase + 32 * wr + lrow) * 1024 + 8 * g;
    const float* xb1 = xb0 + 16 * 1024;
    // per-wave W base for this (wc, g, lrow): fragment unit addressing
    const char* wbase = ws + W1H_OFF + (u32)(4 * wc) * 2048u + (u32)g * 256u + (u32)lrow * 16u;

    float4 xc0 = *(const float4*)(xb0);
    float4 xc1 = *(const float4*)(xb0 + 4);
    float4 xc2 = *(const float4*)(xb1);
    float4 xc3 = *(const float4*)(xb1 + 4);

    for (int c = 0; c < 16; c++) {
#pragma unroll
      for (int ks = 0; ks < 2; ks++) {
        half8 ah0, al0, ah1, al1;
        split8(xc0, xc1, ah0, al0);
        split8(xc2, xc3, ah1, al1);
        // issue next X loads (WAR on xc regs is safe; consumed by split above)
        if (!(c == 15 && ks == 1)) {
          const int off = c * 64 + (ks + 1) * 32;   // next ks (or next chunk's ks0)
          xc0 = *(const float4*)(xb0 + off);
          xc1 = *(const float4*)(xb0 + off + 4);
          xc2 = *(const float4*)(xb1 + off);
          xc3 = *(const float4*)(xb1 + off + 4);
        }
        const char* wb = wbase + (u32)c * 16384u + (u32)ks * 1024u;
#pragma unroll
        for (int tc = 0; tc < 4; tc++) {
          half8 bh = *(const half8*)(wb + tc * 2048);
          half8 bl = *(const half8*)(wb + 262144 + tc * 2048);
          mainA[0][tc]  = mfma16(ah0, bh, mainA[0][tc]);
          crossA[0][tc] = mfma16(ah0, bl, crossA[0][tc]);
          crossA[0][tc] = mfma16(al0, bh, crossA[0][tc]);
          mainA[1][tc]  = mfma16(ah1, bh, mainA[1][tc]);
          crossA[1][tc] = mfma16(ah1, bl, crossA[1][tc]);
          crossA[1][tc] = mfma16(al1, bh, crossA[1][tc]);
        }
      }
    }
  }
  // h1 epilogue -> Hb (first LDS use; no prior barrier needed)
#pragma unroll
  for (int ti = 0; ti < 2; ti++)
#pragma unroll
    for (int tc = 0; tc < 4; tc++) {
      const int col = 64 * wc + 16 * tc + lrow;
      const float bb = b1[col];
#pragma unroll
      for (int r = 0; r < 4; r++) {
        const int row = 32 * wr + 16 * ti + 4 * g + r;
        Hb[row * 132 + col] =
            fmaxf((mainA[ti][tc][r] + crossA[ti][tc][r] * 4.8828125e-4f) * 0.03125f + bb,
                  0.0f);
        mainA[ti][tc][r] = 0.0f; crossA[ti][tc][r] = 0.0f;
      }
    }
  __syncthreads();

  // ===== layer 2: h2 = relu(h1 @ W2 + b2), K=128 ======
  {
    const char* wbase = ws + W2H_OFF + (u32)(4 * wc) * 1024u + (u32)g * 256u + (u32)lrow * 16u;
    for (int cc = 0; cc < 4; cc++) {
      half8 ah[2], al[2];
#pragma unroll
      for (int ti = 0; ti < 2; ti++) {
        const float* hp = Hb + (32 * wr + 16 * ti + lrow) * 132 + cc * 32 + 8 * g;
        split8(*(const float4*)hp, *(const float4*)(hp + 4), ah[ti], al[ti]);
      }
      const char* wb = wbase + (u32)cc * 8192u;
#pragma unroll
      for (int tc = 0; tc < 4; tc++) {
        half8 bh = *(const half8*)(wb + tc * 1024);
        half8 bl = *(const half8*)(wb + 32768 + tc * 1024);
#pragma unroll
        for (int ti = 0; ti < 2; ti++) {
          mainA[ti][tc]  = mfma16(ah[ti], bh, mainA[ti][tc]);
          crossA[ti][tc] = mfma16(ah[ti], bl, crossA[ti][tc]);
          crossA[ti][tc] = mfma16(al[ti], bh, crossA[ti][tc]);
        }
      }
    }
  }
  __syncthreads();   // all h1 reads done
  // h2 epilogue (overlays h1)
#pragma unroll
  for (int ti = 0; ti < 2; ti++)
#pragma unroll
    for (int tc = 0; tc < 4; tc++) {
      const int col = 64 * wc + 16 * tc + lrow;
      const float bb = b2[col];
#pragma unroll
      for (int r = 0; r < 4; r++) {
        const int row = 32 * wr + 16 * ti + 4 * g + r;
        Hb[row * 132 + col] =
            fmaxf((mainA[ti][tc][r] + crossA[ti][tc][r] * 4.8828125e-4f) * 0.03125f + bb,
                  0.0f);
        mainA[ti][tc][r] = 0.0f; crossA[ti][tc][r] = 0.0f;
      }
    }
  __syncthreads();

  // ===== layer 3: logits = h2 @ W3 + b3, 96 (94) cols ======
  f32x4 main3[2][3], cross3[2][3];
#pragma unroll
  for (int ti = 0; ti < 2; ti++)
#pragma unroll
    for (int tc = 0; tc < 3; tc++)
#pragma unroll
      for (int r = 0; r < 4; r++) { main3[ti][tc][r] = 0.0f; cross3[ti][tc][r] = 0.0f; }
  {
    const char* wbase = ws + W3H_OFF + (u32)(3 * wc) * 1024u + (u32)g * 256u + (u32)lrow * 16u;
    for (int cc = 0; cc < 4; cc++) {
      half8 ah[2], al[2];
#pragma unroll
      for (int ti = 0; ti < 2; ti++) {
        const float* hp = Hb + (32 * wr + 16 * ti + lrow) * 132 + cc * 32 + 8 * g;
        split8(*(const float4*)hp, *(const float4*)(hp + 4), ah[ti], al[ti]);
      }
      const char* wb = wbase + (u32)cc * 6144u;
#pragma unroll
      for (int tc = 0; tc < 3; tc++) {
        half8 bh = *(const half8*)(wb + tc * 1024);
        half8 bl = *(const half8*)(wb + 24576 + tc * 1024);
#pragma unroll
        for (int ti = 0; ti < 2; ti++) {
          main3[ti][tc]  = mfma16(ah[ti], bh, main3[ti][tc]);
          cross3[ti][tc] = mfma16(ah[ti], bl, cross3[ti][tc]);
          cross3[ti][tc] = mfma16(al[ti], bh, cross3[ti][tc]);
        }
      }
    }
  }
  __syncthreads();   // all h2 reads done

  // logits epilogue -> Ls (overlays Hb)
  float* Ls = (float*)smem;                 // [64][97]
#pragma unroll
  for (int ti = 0; ti < 2; ti++)
#pragma unroll
    for (int tc = 0; tc < 3; tc++) {
      const int col = 48 * wc + 16 * tc + lrow;
      const float bb = (col < 94) ? b3[col] : 0.0f;
#pragma unroll
      for (int r = 0; r < 4; r++) {
        const int row = 32 * wr + 16 * ti + 4 * g + r;
        Ls[row * 97 + col] =
            (main3[ti][tc][r] + cross3[ti][tc][r] * 4.8828125e-4f) * 0.03125f + bb;
      }
    }
  __syncthreads();

  // ===== sampling: 4 lanes per row, mask direct from global =====
  {
    const int row = 16 * wid + lrow;        // 0..63
    const int q = g;                        // 0..3
    const int* amg = AM + (size_t)(rowBase + row) * 94;
    const float* ls = Ls + row * 97;
    const float NI = -__builtin_huge_valf();

    int amv1[12], amv2[12];
    int s0 = 0, s1 = 0;
#pragma unroll
    for (int k = 0; k < 12; k++) {
      const int a = q + 4 * k;
      amv1[k] = (a < NACT) ? amg[a] : 0;
      amv2[k] = (a < NACT) ? amg[NACT + a] : 0;
      s0 += amv1[k]; s1 += amv2[k];
    }
    s0 += __shfl_xor(s0, 16); s0 += __shfl_xor(s0, 32);
    s1 += __shfl_xor(s1, 16); s1 += __shfl_xor(s1, 32);
    const int am0 = amg[0], amN = amg[NACT];
    const bool fp1 = (s0 == 1) && (am0 == 1);
    const bool fp2 = (s1 == 1) && (amN == 1);
    const u32 growA = (u32)(rowBase + row) * 47u;

    u64 best = 0;
#pragma unroll
    for (int k = 0; k < 12; k++) {
      const int a = q + 4 * k;
      if (a >= NACT) break;
      float l = (amv1[k] != 0) ? ls[a] : NI;
      if (fp2 && !fp1 && a == 0) l = NI;
      float v = l + gumbel_at(K1A, K1B, growA + (u32)a);
      u64 key = ((u64)fmono(v) << 6) | (u32)(63 - a);
      if (key > best) best = key;
    }
    u64 o = __shfl_xor(best, 16); if (o > best) best = o;
    o = __shfl_xor(best, 32); if (o > best) best = o;
    const int a1 = fp1 ? 0 : (63 - (int)(best & 63u));

    const bool sw1 = (a1 >= 1) && (a1 <= 6);
    const bool mv1 = (a1 >= 27);
    best = 0;
#pragma unroll
    for (int k = 0; k < 12; k++) {
      const int a = q + 4 * k;
      if (a >= NACT) break;
      float l = (amv2[k] != 0) ? ls[NACT + a] : NI;
      bool extra = (sw1 && a == a1) || (mv1 && a >= 27 && a < 46);
      if ((fp1 && !fp2 && a == 0) || (!fp1 && !fp2 && extra)) l = NI;
      float v = l + gumbel_at(K2A, K2B, growA + (u32)a);
      u64 key = ((u64)fmono(v) << 6) | (u32)(63 - a);
      if (key > best) best = key;
    }
    o = __shfl_xor(best, 16); if (o > best) best = o;
    o = __shfl_xor(best, 32); if (o > best) best = o;
    const int a2 = fp2 ? 0 : (63 - (int)(best & 63u));

    if (q == 0) {
      out[(size_t)(rowBase + row) * 2 + 0] = a1;
      out[(size_t)(rowBase + row) * 2 + 1] = a2;
    }
  }
}

// ---------------- fallback: round-6 proven f32 kernel (used if ws too small)
__global__ __launch_bounds__(256)
void fused_policy_v1(const float* __restrict__ X,  const int* __restrict__ AM,
                     const float* __restrict__ W1, const float* __restrict__ b1,
                     const float* __restrict__ W2, const float* __restrict__ b2,
                     const float* __restrict__ W3, const float* __restrict__ b3,
                     int* __restrict__ out) {
  __shared__ alignas(16) char smem[59904];
  float (*HT)[68]   = reinterpret_cast<float (*)[68]>(smem);
  float (*Wst)[128] = reinterpret_cast<float (*)[128]>(smem + 34816);
  float (*Ws3)[96]  = reinterpret_cast<float (*)[96]>(smem + 34816);
  float (*Xt)[68]   = reinterpret_cast<float (*)[68]>(smem + 51200);
  float (*Lsr)[97]  = reinterpret_cast<float (*)[97]>(smem);
  int*   Amf        = reinterpret_cast<int*>(smem + 34816);

  const int t = threadIdx.x;
  const int rowBase = blockIdx.x * 64;
  const int tx = t & 31, ty = t >> 5;
  const int c0 = tx * 4, r0 = ty * 8;

  float accf[8][4]; double accd[8][4];
#pragma unroll
  for (int i = 0; i < 8; i++)
#pragma unroll
    for (int j = 0; j < 4; j++) { accf[i][j] = 0.0f; accd[i][j] = 0.0; }

  for (int k0 = 0; k0 < 1024; k0 += 32) {
#pragma unroll
    for (int i = 0; i < 2; i++) {
      int idx = t + i * 256;
      int row = idx >> 3, kb = (idx & 7) * 4;
      float4 v = *reinterpret_cast<const float4*>(X + (size_t)(rowBase + row) * 1024 + k0 + kb);
      Xt[kb + 0][row] = v.x; Xt[kb + 1][row] = v.y;
      Xt[kb + 2][row] = v.z; Xt[kb + 3][row] = v.w;
    }
#pragma unroll
    for (int i = 0; i < 4; i++) {
      int idx = t + i * 256;
      int kr = idx >> 5, c4 = (idx & 31) * 4;
      *reinterpret_cast<float4*>(&Wst[kr][c4]) =
          *reinterpret_cast<const float4*>(W1 + (size_t)(k0 + kr) * 128 + c4);
    }
    __syncthreads();
#pragma unroll
    for (int kk = 0; kk < 32; kk++) {
      float4 a0 = *reinterpret_cast<const float4*>(&Xt[kk][r0]);
      float4 a1 = *reinterpret_cast<const float4*>(&Xt[kk][r0 + 4]);
      float4 b  = *reinterpret_cast<const float4*>(&Wst[kk][c0]);
      float av[8] = {a0.x, a0.y, a0.z, a0.w, a1.x, a1.y, a1.z, a1.w};
      float bv[4] = {b.x, b.y, b.z, b.w};
#pragma unroll
      for (int i = 0; i < 8; i++)
#pragma unroll
        for (int j = 0; j < 4; j++) accf[i][j] = fmaf(av[i], bv[j], accf[i][j]);
    }
    if ((k0 & 63) == 32) {
#pragma unroll
      for (int i = 0; i < 8; i++)
#pragma unroll
        for (int j = 0; j < 4; j++) { accd[i][j] += (double)accf[i][j]; accf[i][j] = 0.0f; }
    }
    __syncthreads();
  }
  {
    const float4 bv = *reinterpret_cast<const float4*>(b1 + c0);
#pragma unroll
    for (int i = 0; i < 8; i++) {
      HT[c0 + 0][r0 + i] = fmaxf((float)accd[i][0] + bv.x, 0.0f);
      HT[c0 + 1][r0 + i] = fmaxf((float)accd[i][1] + bv.y, 0.0f);
      HT[c0 + 2][r0 + i] = fmaxf((float)accd[i][2] + bv.z, 0.0f);
      HT[c0 + 3][r0 + i] = fmaxf((float)accd[i][3] + bv.w, 0.0f);
    }
  }
  __syncthreads();

#pragma unroll
  for (int i = 0; i < 8; i++)
#pragma unroll
    for (int j = 0; j < 4; j++) { accf[i][j] = 0.0f; accd[i][j] = 0.0; }
  for (int k0 = 0; k0 < 128; k0 += 32) {
#pragma unroll
    for (int i = 0; i < 4; i++) {
      int idx = t + i * 256;
      int kr = idx >> 5, c4 = (idx & 31) * 4;
      *reinterpret_cast<float4*>(&Wst[kr][c4]) =
          *reinterpret_cast<const float4*>(W2 + (size_t)(k0 + kr) * 128 + c4);
    }
    __syncthreads();
#pragma unroll
    for (int kk = 0; kk < 32; kk++) {
      float4 a0 = *reinterpret_cast<const float4*>(&HT[k0 + kk][r0]);
      float4 a1 = *reinterpret_cast<const float4*>(&HT[k0 + kk][r0 + 4]);
      float4 b  = *reinterpret_cast<const float4*>(&Wst[kk][c0]);
      float av[8] = {a0.x, a0.y, a0.z, a0.w, a1.x, a1.y, a1.z, a1.w};
      float bv[4] = {b.x, b.y, b.z, b.w};
#pragma unroll
      for (int i = 0; i < 8; i++)
#pragma unroll
        for (int j = 0; j < 4; j++) accf[i][j] = fmaf(av[i], bv[j], accf[i][j]);
    }
    if ((k0 & 63) == 32) {
#pragma unroll
      for (int i = 0; i < 8; i++)
#pragma unroll
        for (int j = 0; j < 4; j++) { accd[i][j] += (double)accf[i][j]; accf[i][j] = 0.0f; }
    }
    __syncthreads();
  }
  {
    const float4 bv = *reinterpret_cast<const float4*>(b2 + c0);
#pragma unroll
    for (int i = 0; i < 8; i++) {
      HT[c0 + 0][r0 + i] = fmaxf((float)accd[i][0] + bv.x, 0.0f);
      HT[c0 + 1][r0 + i] = fmaxf((float)accd[i][1] + bv.y, 0.0f);
      HT[c0 + 2][r0 + i] = fmaxf((float)accd[i][2] + bv.z, 0.0f);
      HT[c0 + 3][r0 + i] = fmaxf((float)accd[i][3] + bv.w, 0.0f);
    }
  }
  __syncthreads();

  const int c3 = tx * 3;
  float acc3f[8][3]; double acc3d[8][3];
#pragma unroll
  for (int i = 0; i < 8; i++)
#pragma unroll
    for (int j = 0; j < 3; j++) { acc3f[i][j] = 0.0f; acc3d[i][j] = 0.0; }
  for (int k0 = 0; k0 < 128; k0 += 32) {
#pragma unroll
    for (int i = 0; i < 12; i++) {
      int idx = t + i * 256;
      int kr = idx / 96, c = idx - kr * 96;
      Ws3[kr][c] = (c < 94) ? W3[(size_t)(k0 + kr) * 94 + c] : 0.0f;
    }
    __syncthreads();
#pragma unroll
    for (int kk = 0; kk < 32; kk++) {
      float4 a0 = *reinterpret_cast<const float4*>(&HT[k0 + kk][r0]);
      float4 a1 = *reinterpret_cast<const float4*>(&HT[k0 + kk][r0 + 4]);
      float b0 = Ws3[kk][c3], b1v = Ws3[kk][c3 + 1], b2v = Ws3[kk][c3 + 2];
      float av[8] = {a0.x, a0.y, a0.z, a0.w, a1.x, a1.y, a1.z, a1.w};
      float bv3[3] = {b0, b1v, b2v};
#pragma unroll
      for (int i = 0; i < 8; i++)
#pragma unroll
        for (int j = 0; j < 3; j++) acc3f[i][j] = fmaf(av[i], bv3[j], acc3f[i][j]);
    }
    if ((k0 & 63) == 32) {
#pragma unroll
      for (int i = 0; i < 8; i++)
#pragma unroll
        for (int j = 0; j < 3; j++) { acc3d[i][j] += (double)acc3f[i][j]; acc3f[i][j] = 0.0f; }
    }
    __syncthreads();
  }
  {
    float b3v[3];
#pragma unroll
    for (int j = 0; j < 3; j++) b3v[j] = (c3 + j < 94) ? b3[c3 + j] : 0.0f;
#pragma unroll
    for (int i = 0; i < 8; i++)
#pragma unroll
      for (int j = 0; j < 3; j++)
        Lsr[r0 + i][c3 + j] = (float)acc3d[i][j] + b3v[j];
  }
#pragma unroll
  for (int i = 0; i < 24; i++) {
    int idx = t + i * 256;
    if (idx < 64 * 94) Amf[idx] = AM[(size_t)rowBase * 94 + idx];
  }
  __syncthreads();

  if (t < 64) {
    const int row = rowBase + t;
    const float NI = -__builtin_huge_valf();
    const int* am = Amf + t * 94;
    int sum0 = 0, sum1 = 0;
    for (int a = 0; a < NACT; a++) { sum0 += am[a]; sum1 += am[NACT + a]; }
    const bool fp1 = (sum0 == 1) && (am[0] == 1);
    const bool fp2 = (sum1 == 1) && (am[NACT] == 1);
    float bestv = NI; int a1s = 0;
    for (int a = 0; a < NACT; a++) {
      float l = (am[a] != 0) ? Lsr[t][a] : NI;
      if (fp2 && !fp1 && a == 0) l = NI;
      float v = l + gumbel_at(K1A, K1B, (u32)row * 47u + (u32)a);
      if (v > bestv) { bestv = v; a1s = a; }
    }
    const int a1 = fp1 ? 0 : a1s;
    const bool sw1 = (a1 >= 1) && (a1 <= 6);
    const bool mv1 = (a1 >= 27) && (a1 <= 46);
    bestv = NI; int a2s = 0;
    for (int a = 0; a < NACT; a++) {
      float l = (am[NACT + a] != 0) ? Lsr[t][NACT + a] : NI;
      bool extra = (sw1 && a == a1) || (mv1 && a >= 27 && a < 46);
      bool m2 = (fp1 && !fp2 && a == 0) || (!fp1 && !fp2 && extra);
      if (m2) l = NI;
      float v = l + gumbel_at(K2A, K2B, (u32)row * 47u + (u32)a);
      if (v > bestv) { bestv = v; a2s = a; }
    }
    const int a2 = fp2 ? 0 : a2s;
    out[(size_t)row * 2 + 0] = a1;
    out[(size_t)row * 2 + 1] = a2;
  }
}

extern "C" void kernel_launch(void* const* d_in, const int* in_sizes, int n_in,
                              void* d_out, int out_size, void* d_ws, size_t ws_size,
                              hipStream_t stream) {
  const float* X  = (const float*)d_in[0];
  const int*   AM = (const int*)d_in[1];
  const float* W1 = (const float*)d_in[2];
  const float* b1 = (const float*)d_in[3];
  const float* W2 = (const float*)d_in[4];
  const float* b2 = (const float*)d_in[5];
  const float* W3 = (const float*)d_in[6];
  const float* b3 = (const float*)d_in[7];
  int* out = (int*)d_out;

  if (ws_size >= (size_t)WS_NEEDED) {
    prep_weights<<<624, 256, 0, stream>>>(W1, W2, W3, (char*)d_ws);
    fused_mfma<<<1024, 256, 0, stream>>>(X, AM, b1, b2, b3, (const char*)d_ws, out);
  } else {
    fused_policy_v1<<<1024, 256, 0, stream>>>(X, AM, W1, b1, W2, b2, W3, b3, out);
  }
}

// Round 11
// 120.351 us; speedup vs baseline: 1.7332x; 1.2560x over previous
//
#include <hip/hip_runtime.h>

typedef unsigned int u32;
typedef unsigned long long u64;
typedef _Float16 f16;
typedef f16 half8 __attribute__((ext_vector_type(8)));
typedef float f32x4 __attribute__((ext_vector_type(4)));

// ---------------- threefry2x32-20 (exact JAX replica, partitionable mode) ----
struct U2 { u32 x, y; };

__host__ __device__ constexpr u32 rotl32(u32 v, int r) {
  return (v << r) | (v >> (32 - r));
}

__host__ __device__ constexpr U2 threefry2x32(u32 k0, u32 k1, u32 c0, u32 c1) {
  u32 ks2 = k0 ^ k1 ^ 0x1BD11BDAu;
  u32 x0 = c0 + k0, x1 = c1 + k1;
#define TFR(r) { x0 += x1; x1 = rotl32(x1, r); x1 ^= x0; }
  TFR(13) TFR(15) TFR(26) TFR(6)
  x0 += k1; x1 += ks2 + 1u;
  TFR(17) TFR(29) TFR(16) TFR(24)
  x0 += ks2; x1 += k0 + 2u;
  TFR(13) TFR(15) TFR(26) TFR(6)
  x0 += k0; x1 += k1 + 3u;
  TFR(17) TFR(29) TFR(16) TFR(24)
  x0 += k1; x1 += ks2 + 4u;
  TFR(13) TFR(15) TFR(26) TFR(6)
  x0 += ks2; x1 += k0 + 5u;
#undef TFR
  return {x0, x1};
}

constexpr U2 SK1 = threefry2x32(0u, 42u, 0u, 0u);   // k1 (for g1)
constexpr U2 SK2 = threefry2x32(0u, 42u, 0u, 1u);   // k2 (for g2)
constexpr u32 K1A = SK1.x, K1B = SK1.y;
constexpr u32 K2A = SK2.x, K2B = SK2.y;

#define NACT 47

__device__ __forceinline__ float gumbel_at(u32 kA, u32 kB, u32 i) {
  U2 r = threefry2x32(kA, kB, 0u, i);
  u32 bits = r.x ^ r.y;
  float f = __uint_as_float(0x3f800000u | (bits >> 9)) - 1.0f;
  f = fmaxf(f, 1.17549435e-38f);
  return -logf(-logf(f));
}

// monotone float->u32 map (handles -inf; no NaN in inputs)
__device__ __forceinline__ u32 fmono(float f) {
  u32 b = __float_as_uint(f);
  return b ^ ((b & 0x80000000u) ? 0xFFFFFFFFu : 0x80000000u);
}

// ---------------- d_ws layout: fragment-unit-major split weights ------------
#define W1H_OFF 0u          // 16 chunks x 16384 B  (chunk = 64k x 128c)
#define W1L_OFF 262144u
#define W2H_OFF 524288u     // 4 chunks x 8192 B    (chunk = 32k x 128c)
#define W2L_OFF 557056u
#define W3H_OFF 589824u     // 4 chunks x 6144 B    (chunk = 32k x 96c)
#define W3L_OFF 614400u
#define WS_NEEDED 638976u

__global__ __launch_bounds__(256)
void prep_weights(const float* __restrict__ W1, const float* __restrict__ W2,
                  const float* __restrict__ W3, char* __restrict__ ws) {
  const int bid = blockIdx.x, t = threadIdx.x;
  if (bid < 512) {                       // W1: 1024x128
    int idx = bid * 256 + t;
    int col = idx & 127, k = idx >> 7;
    float w = W1[(size_t)k * 128 + col] * 32.0f;
    f16 h = (f16)w;
    f16 l = (f16)((w - (float)h) * 2048.0f);
    u32 addr = (u32)(k >> 6) * 16384u + (u32)(col >> 4) * 2048u +
               (u32)((k >> 5) & 1) * 1024u + (u32)((k >> 3) & 3) * 256u +
               (u32)(col & 15) * 16u + (u32)(k & 7) * 2u;
    *(f16*)(ws + W1H_OFF + addr) = h;
    *(f16*)(ws + W1L_OFF + addr) = l;
  } else if (bid < 576) {                // W2: 128x128
    int idx = (bid - 512) * 256 + t;
    int col = idx & 127, k = idx >> 7;
    float w = W2[(size_t)k * 128 + col] * 32.0f;
    f16 h = (f16)w;
    f16 l = (f16)((w - (float)h) * 2048.0f);
    u32 addr = (u32)(k >> 5) * 8192u + (u32)(col >> 4) * 1024u +
               (u32)((k >> 3) & 3) * 256u + (u32)(col & 15) * 16u + (u32)(k & 7) * 2u;
    *(f16*)(ws + W2H_OFF + addr) = h;
    *(f16*)(ws + W2L_OFF + addr) = l;
  } else {                               // W3: 128x94 -> padded 96 cols
    int idx = (bid - 576) * 256 + t;     // 48 blocks * 256 = 12288 = 128*96
    int col = idx % 96, k = idx / 96;
    float w = (col < 94) ? W3[(size_t)k * 94 + col] * 32.0f : 0.0f;
    f16 h = (f16)w;
    f16 l = (f16)((w - (float)h) * 2048.0f);
    u32 addr = (u32)(k >> 5) * 6144u + (u32)(col >> 4) * 1024u +
               (u32)((k >> 3) & 3) * 256u + (u32)(col & 15) * 16u + (u32)(k & 7) * 2u;
    *(f16*)(ws + W3H_OFF + addr) = h;
    *(f16*)(ws + W3L_OFF + addr) = l;
  }
}

__device__ __forceinline__ f32x4 mfma16(half8 a, half8 b, f32x4 c) {
  return __builtin_amdgcn_mfma_f32_16x16x32_f16(a, b, c, 0, 0, 0);
}

__device__ __forceinline__ void split8(float4 v0, float4 v1, half8& hi, half8& lo) {
  float xs[8] = {v0.x, v0.y, v0.z, v0.w, v1.x, v1.y, v1.z, v1.w};
#pragma unroll
  for (int i = 0; i < 8; i++) {
    f16 h = (f16)xs[i];
    hi[i] = h;
    lo[i] = (f16)((xs[i] - (float)h) * 2048.0f);
  }
}

// ---------------- MFMA fused policy kernel, LDS-staged X ----------------
// 64 rows/block, 256 threads = 4 waves in 2x2 (wr rows, wc cols). 4 blocks/CU.
// L1: X staged per 32-k chunk into LDS as pre-split f16 hi/lo (stride-72B rows,
// 2-way bank alias = free); W read global(L2)->reg coalesced 1KB fragments; f32
// MFMA accumulate across all K. X buffers (2x9216B) overlay the dead Hb region.
// LDS total 33792 B -> 4 blocks/CU.
__global__ __launch_bounds__(256, 4)
void fused_mfma(const float* __restrict__ X, const int* __restrict__ AM,
                const float* __restrict__ b1, const float* __restrict__ b2,
                const float* __restrict__ b3, const char* __restrict__ ws,
                int* __restrict__ out) {
  __shared__ __align__(16) char smem[33792];   // Xbufs (L1) / Hb f32[64][132] / Ls
  const int t = threadIdx.x;
  const int lane = t & 63, wid = t >> 6;
  const int lrow = lane & 15, g = lane >> 4;
  const int wr = wid & 1, wc = wid >> 1;
  const int rowBase = blockIdx.x * 64;
  float* Hb = (float*)smem;

  f32x4 mainA[2][4], crossA[2][4];
#pragma unroll
  for (int ti = 0; ti < 2; ti++)
#pragma unroll
    for (int tc = 0; tc < 4; tc++)
#pragma unroll
      for (int r = 0; r < 4; r++) { mainA[ti][tc][r] = 0.0f; crossA[ti][tc][r] = 0.0f; }

  // ===== layer 1: h1 = relu(X @ W1 + b1), K=1024, LDS-staged X =====
  {
    // X buffers: buf b at offset b*9216; hi [0,4608), lo [4608,9216). Row stride 72B.
    const int rowS = t >> 2, gq = t & 3;                  // stage role: 8 floats/thread
    const float* xsrc = X + (size_t)(rowBase + rowS) * 1024 + gq * 8;
    const u32 wadr = (u32)rowS * 72u + (u32)gq * 16u;     // ds_write base (hi)
    // compute-side read bases (per ti)
    const u32 radr0 = (u32)(32 * wr + lrow) * 72u + (u32)g * 16u;
    const u32 radr1 = (u32)(32 * wr + 16 + lrow) * 72u + (u32)g * 16u;
    const char* wbase = ws + W1H_OFF + (u32)(4 * wc) * 2048u + (u32)g * 256u + (u32)lrow * 16u;

    float4 sx0, sx1;
    // prologue: stage chunk 0, prefetch chunk 1 into regs
    sx0 = *(const float4*)(xsrc);
    sx1 = *(const float4*)(xsrc + 4);
    {
      half8 h, l;
      split8(sx0, sx1, h, l);
      *(half8*)(smem + wadr) = h;
      *(half8*)(smem + wadr + 4608) = l;
    }
    sx0 = *(const float4*)(xsrc + 32);
    sx1 = *(const float4*)(xsrc + 36);
    __syncthreads();                                       // buf0 ready

    for (int ks = 0; ks < 32; ks++) {
      const u32 cur = (u32)(ks & 1) * 9216u;
      // stage chunk ks+1 into the other buffer; prefetch chunk ks+2
      if (ks < 31) {
        const u32 nxt = (u32)((ks + 1) & 1) * 9216u;
        half8 h, l;
        split8(sx0, sx1, h, l);
        *(half8*)(smem + nxt + wadr) = h;
        *(half8*)(smem + nxt + wadr + 4608) = l;
        if (ks < 30) {
          sx0 = *(const float4*)(xsrc + (ks + 2) * 32);
          sx1 = *(const float4*)(xsrc + (ks + 2) * 32 + 4);
        }
      }
      // compute from buf[cur]
      half8 ah0 = *(const half8*)(smem + cur + radr0);
      half8 al0 = *(const half8*)(smem + cur + radr0 + 4608);
      half8 ah1 = *(const half8*)(smem + cur + radr1);
      half8 al1 = *(const half8*)(smem + cur + radr1 + 4608);
      const char* wb = wbase + (u32)(ks >> 1) * 16384u + (u32)(ks & 1) * 1024u;
#pragma unroll
      for (int tc = 0; tc < 4; tc++) {
        half8 bh = *(const half8*)(wb + tc * 2048);
        half8 bl = *(const half8*)(wb + 262144 + tc * 2048);
        mainA[0][tc]  = mfma16(ah0, bh, mainA[0][tc]);
        crossA[0][tc] = mfma16(ah0, bl, crossA[0][tc]);
        crossA[0][tc] = mfma16(al0, bh, crossA[0][tc]);
        mainA[1][tc]  = mfma16(ah1, bh, mainA[1][tc]);
        crossA[1][tc] = mfma16(ah1, bl, crossA[1][tc]);
        mainA[1][tc]  = mainA[1][tc];   // keep order stable
        crossA[1][tc] = mfma16(al1, bh, crossA[1][tc]);
      }
      __syncthreads();   // all reads of buf[cur] done; buf[nxt] writes visible
    }
  }
  // h1 epilogue -> Hb (overlays X buffers; barrier above guarantees reads done)
#pragma unroll
  for (int ti = 0; ti < 2; ti++)
#pragma unroll
    for (int tc = 0; tc < 4; tc++) {
      const int col = 64 * wc + 16 * tc + lrow;
      const float bb = b1[col];
#pragma unroll
      for (int r = 0; r < 4; r++) {
        const int row = 32 * wr + 16 * ti + 4 * g + r;
        Hb[row * 132 + col] =
            fmaxf((mainA[ti][tc][r] + crossA[ti][tc][r] * 4.8828125e-4f) * 0.03125f + bb,
                  0.0f);
        mainA[ti][tc][r] = 0.0f; crossA[ti][tc][r] = 0.0f;
      }
    }
  __syncthreads();

  // ===== layer 2: h2 = relu(h1 @ W2 + b2), K=128 ======
  {
    const char* wbase = ws + W2H_OFF + (u32)(4 * wc) * 1024u + (u32)g * 256u + (u32)lrow * 16u;
    for (int cc = 0; cc < 4; cc++) {
      half8 ah[2], al[2];
#pragma unroll
      for (int ti = 0; ti < 2; ti++) {
        const float* hp = Hb + (32 * wr + 16 * ti + lrow) * 132 + cc * 32 + 8 * g;
        split8(*(const float4*)hp, *(const float4*)(hp + 4), ah[ti], al[ti]);
      }
      const char* wb = wbase + (u32)cc * 8192u;
#pragma unroll
      for (int tc = 0; tc < 4; tc++) {
        half8 bh = *(const half8*)(wb + tc * 1024);
        half8 bl = *(const half8*)(wb + 32768 + tc * 1024);
#pragma unroll
        for (int ti = 0; ti < 2; ti++) {
          mainA[ti][tc]  = mfma16(ah[ti], bh, mainA[ti][tc]);
          crossA[ti][tc] = mfma16(ah[ti], bl, crossA[ti][tc]);
          crossA[ti][tc] = mfma16(al[ti], bh, crossA[ti][tc]);
        }
      }
    }
  }
  __syncthreads();   // all h1 reads done
  // h2 epilogue (overlays h1)
#pragma unroll
  for (int ti = 0; ti < 2; ti++)
#pragma unroll
    for (int tc = 0; tc < 4; tc++) {
      const int col = 64 * wc + 16 * tc + lrow;
      const float bb = b2[col];
#pragma unroll
      for (int r = 0; r < 4; r++) {
        const int row = 32 * wr + 16 * ti + 4 * g + r;
        Hb[row * 132 + col] =
            fmaxf((mainA[ti][tc][r] + crossA[ti][tc][r] * 4.8828125e-4f) * 0.03125f + bb,
                  0.0f);
        mainA[ti][tc][r] = 0.0f; crossA[ti][tc][r] = 0.0f;
      }
    }
  __syncthreads();

  // ===== layer 3: logits = h2 @ W3 + b3, 96 (94) cols ======
  f32x4 main3[2][3], cross3[2][3];
#pragma unroll
  for (int ti = 0; ti < 2; ti++)
#pragma unroll
    for (int tc = 0; tc < 3; tc++)
#pragma unroll
      for (int r = 0; r < 4; r++) { main3[ti][tc][r] = 0.0f; cross3[ti][tc][r] = 0.0f; }
  {
    const char* wbase = ws + W3H_OFF + (u32)(3 * wc) * 1024u + (u32)g * 256u + (u32)lrow * 16u;
    for (int cc = 0; cc < 4; cc++) {
      half8 ah[2], al[2];
#pragma unroll
      for (int ti = 0; ti < 2; ti++) {
        const float* hp = Hb + (32 * wr + 16 * ti + lrow) * 132 + cc * 32 + 8 * g;
        split8(*(const float4*)hp, *(const float4*)(hp + 4), ah[ti], al[ti]);
      }
      const char* wb = wbase + (u32)cc * 6144u;
#pragma unroll
      for (int tc = 0; tc < 3; tc++) {
        half8 bh = *(const half8*)(wb + tc * 1024);
        half8 bl = *(const half8*)(wb + 24576 + tc * 1024);
#pragma unroll
        for (int ti = 0; ti < 2; ti++) {
          main3[ti][tc]  = mfma16(ah[ti], bh, main3[ti][tc]);
          cross3[ti][tc] = mfma16(ah[ti], bl, cross3[ti][tc]);
          cross3[ti][tc] = mfma16(al[ti], bh, cross3[ti][tc]);
        }
      }
    }
  }
  __syncthreads();   // all h2 reads done

  // logits epilogue -> Ls (overlays Hb)
  float* Ls = (float*)smem;                 // [64][97]
#pragma unroll
  for (int ti = 0; ti < 2; ti++)
#pragma unroll
    for (int tc = 0; tc < 3; tc++) {
      const int col = 48 * wc + 16 * tc + lrow;
      const float bb = (col < 94) ? b3[col] : 0.0f;
#pragma unroll
      for (int r = 0; r < 4; r++) {
        const int row = 32 * wr + 16 * ti + 4 * g + r;
        Ls[row * 97 + col] =
            (main3[ti][tc][r] + cross3[ti][tc][r] * 4.8828125e-4f) * 0.03125f + bb;
      }
    }
  __syncthreads();

  // ===== sampling: 4 lanes per row, mask direct from global =====
  {
    const int row = 16 * wid + lrow;        // 0..63
    const int q = g;                        // 0..3
    const int* amg = AM + (size_t)(rowBase + row) * 94;
    const float* ls = Ls + row * 97;
    const float NI = -__builtin_huge_valf();

    int amv1[12], amv2[12];
    int s0 = 0, s1 = 0;
#pragma unroll
    for (int k = 0; k < 12; k++) {
      const int a = q + 4 * k;
      amv1[k] = (a < NACT) ? amg[a] : 0;
      amv2[k] = (a < NACT) ? amg[NACT + a] : 0;
      s0 += amv1[k]; s1 += amv2[k];
    }
    s0 += __shfl_xor(s0, 16); s0 += __shfl_xor(s0, 32);
    s1 += __shfl_xor(s1, 16); s1 += __shfl_xor(s1, 32);
    const int am0 = amg[0], amN = amg[NACT];
    const bool fp1 = (s0 == 1) && (am0 == 1);
    const bool fp2 = (s1 == 1) && (amN == 1);
    const u32 growA = (u32)(rowBase + row) * 47u;

    u64 best = 0;
#pragma unroll
    for (int k = 0; k < 12; k++) {
      const int a = q + 4 * k;
      if (a >= NACT) break;
      float l = (amv1[k] != 0) ? ls[a] : NI;
      if (fp2 && !fp1 && a == 0) l = NI;
      float v = l + gumbel_at(K1A, K1B, growA + (u32)a);
      u64 key = ((u64)fmono(v) << 6) | (u32)(63 - a);
      if (key > best) best = key;
    }
    u64 o = __shfl_xor(best, 16); if (o > best) best = o;
    o = __shfl_xor(best, 32); if (o > best) best = o;
    const int a1 = fp1 ? 0 : (63 - (int)(best & 63u));

    const bool sw1 = (a1 >= 1) && (a1 <= 6);
    const bool mv1 = (a1 >= 27);
    best = 0;
#pragma unroll
    for (int k = 0; k < 12; k++) {
      const int a = q + 4 * k;
      if (a >= NACT) break;
      float l = (amv2[k] != 0) ? ls[NACT + a] : NI;
      bool extra = (sw1 && a == a1) || (mv1 && a >= 27 && a < 46);
      if ((fp1 && !fp2 && a == 0) || (!fp1 && !fp2 && extra)) l = NI;
      float v = l + gumbel_at(K2A, K2B, growA + (u32)a);
      u64 key = ((u64)fmono(v) << 6) | (u32)(63 - a);
      if (key > best) best = key;
    }
    o = __shfl_xor(best, 16); if (o > best) best = o;
    o = __shfl_xor(best, 32); if (o > best) best = o;
    const int a2 = fp2 ? 0 : (63 - (int)(best & 63u));

    if (q == 0) {
      out[(size_t)(rowBase + row) * 2 + 0] = a1;
      out[(size_t)(rowBase + row) * 2 + 1] = a2;
    }
  }
}

// ---------------- fallback: round-6 proven f32 kernel (used if ws too small)
__global__ __launch_bounds__(256)
void fused_policy_v1(const float* __restrict__ X,  const int* __restrict__ AM,
                     const float* __restrict__ W1, const float* __restrict__ b1,
                     const float* __restrict__ W2, const float* __restrict__ b2,
                     const float* __restrict__ W3, const float* __restrict__ b3,
                     int* __restrict__ out) {
  __shared__ alignas(16) char smem[59904];
  float (*HT)[68]   = reinterpret_cast<float (*)[68]>(smem);
  float (*Wst)[128] = reinterpret_cast<float (*)[128]>(smem + 34816);
  float (*Ws3)[96]  = reinterpret_cast<float (*)[96]>(smem + 34816);
  float (*Xt)[68]   = reinterpret_cast<float (*)[68]>(smem + 51200);
  float (*Lsr)[97]  = reinterpret_cast<float (*)[97]>(smem);
  int*   Amf        = reinterpret_cast<int*>(smem + 34816);

  const int t = threadIdx.x;
  const int rowBase = blockIdx.x * 64;
  const int tx = t & 31, ty = t >> 5;
  const int c0 = tx * 4, r0 = ty * 8;

  float accf[8][4]; double accd[8][4];
#pragma unroll
  for (int i = 0; i < 8; i++)
#pragma unroll
    for (int j = 0; j < 4; j++) { accf[i][j] = 0.0f; accd[i][j] = 0.0; }

  for (int k0 = 0; k0 < 1024; k0 += 32) {
#pragma unroll
    for (int i = 0; i < 2; i++) {
      int idx = t + i * 256;
      int row = idx >> 3, kb = (idx & 7) * 4;
      float4 v = *reinterpret_cast<const float4*>(X + (size_t)(rowBase + row) * 1024 + k0 + kb);
      Xt[kb + 0][row] = v.x; Xt[kb + 1][row] = v.y;
      Xt[kb + 2][row] = v.z; Xt[kb + 3][row] = v.w;
    }
#pragma unroll
    for (int i = 0; i < 4; i++) {
      int idx = t + i * 256;
      int kr = idx >> 5, c4 = (idx & 31) * 4;
      *reinterpret_cast<float4*>(&Wst[kr][c4]) =
          *reinterpret_cast<const float4*>(W1 + (size_t)(k0 + kr) * 128 + c4);
    }
    __syncthreads();
#pragma unroll
    for (int kk = 0; kk < 32; kk++) {
      float4 a0 = *reinterpret_cast<const float4*>(&Xt[kk][r0]);
      float4 a1 = *reinterpret_cast<const float4*>(&Xt[kk][r0 + 4]);
      float4 b  = *reinterpret_cast<const float4*>(&Wst[kk][c0]);
      float av[8] = {a0.x, a0.y, a0.z, a0.w, a1.x, a1.y, a1.z, a1.w};
      float bv[4] = {b.x, b.y, b.z, b.w};
#pragma unroll
      for (int i = 0; i < 8; i++)
#pragma unroll
        for (int j = 0; j < 4; j++) accf[i][j] = fmaf(av[i], bv[j], accf[i][j]);
    }
    if ((k0 & 63) == 32) {
#pragma unroll
      for (int i = 0; i < 8; i++)
#pragma unroll
        for (int j = 0; j < 4; j++) { accd[i][j] += (double)accf[i][j]; accf[i][j] = 0.0f; }
    }
    __syncthreads();
  }
  {
    const float4 bv = *reinterpret_cast<const float4*>(b1 + c0);
#pragma unroll
    for (int i = 0; i < 8; i++) {
      HT[c0 + 0][r0 + i] = fmaxf((float)accd[i][0] + bv.x, 0.0f);
      HT[c0 + 1][r0 + i] = fmaxf((float)accd[i][1] + bv.y, 0.0f);
      HT[c0 + 2][r0 + i] = fmaxf((float)accd[i][2] + bv.z, 0.0f);
      HT[c0 + 3][r0 + i] = fmaxf((float)accd[i][3] + bv.w, 0.0f);
    }
  }
  __syncthreads();

#pragma unroll
  for (int i = 0; i < 8; i++)
#pragma unroll
    for (int j = 0; j < 4; j++) { accf[i][j] = 0.0f; accd[i][j] = 0.0; }
  for (int k0 = 0; k0 < 128; k0 += 32) {
#pragma unroll
    for (int i = 0; i < 4; i++) {
      int idx = t + i * 256;
      int kr = idx >> 5, c4 = (idx & 31) * 4;
      *reinterpret_cast<float4*>(&Wst[kr][c4]) =
          *reinterpret_cast<const float4*>(W2 + (size_t)(k0 + kr) * 128 + c4);
    }
    __syncthreads();
#pragma unroll
    for (int kk = 0; kk < 32; kk++) {
      float4 a0 = *reinterpret_cast<const float4*>(&HT[k0 + kk][r0]);
      float4 a1 = *reinterpret_cast<const float4*>(&HT[k0 + kk][r0 + 4]);
      float4 b  = *reinterpret_cast<const float4*>(&Wst[kk][c0]);
      float av[8] = {a0.x, a0.y, a0.z, a0.w, a1.x, a1.y, a1.z, a1.w};
      float bv[4] = {b.x, b.y, b.z, b.w};
#pragma unroll
      for (int i = 0; i < 8; i++)
#pragma unroll
        for (int j = 0; j < 4; j++) accf[i][j] = fmaf(av[i], bv[j], accf[i][j]);
    }
    if ((k0 & 63) == 32) {
#pragma unroll
      for (int i = 0; i < 8; i++)
#pragma unroll
        for (int j = 0; j < 4; j++) { accd[i][j] += (double)accf[i][j]; accf[i][j] = 0.0f; }
    }
    __syncthreads();
  }
  {
    const float4 bv = *reinterpret_cast<const float4*>(b2 + c0);
#pragma unroll
    for (int i = 0; i < 8; i++) {
      HT[c0 + 0][r0 + i] = fmaxf((float)accd[i][0] + bv.x, 0.0f);
      HT[c0 + 1][r0 + i] = fmaxf((float)accd[i][1] + bv.y, 0.0f);
      HT[c0 + 2][r0 + i] = fmaxf((float)accd[i][2] + bv.z, 0.0f);
      HT[c0 + 3][r0 + i] = fmaxf((float)accd[i][3] + bv.w, 0.0f);
    }
  }
  __syncthreads();

  const int c3 = tx * 3;
  float acc3f[8][3]; double acc3d[8][3];
#pragma unroll
  for (int i = 0; i < 8; i++)
#pragma unroll
    for (int j = 0; j < 3; j++) { acc3f[i][j] = 0.0f; acc3d[i][j] = 0.0; }
  for (int k0 = 0; k0 < 128; k0 += 32) {
#pragma unroll
    for (int i = 0; i < 12; i++) {
      int idx = t + i * 256;
      int kr = idx / 96, c = idx - kr * 96;
      Ws3[kr][c] = (c < 94) ? W3[(size_t)(k0 + kr) * 94 + c] : 0.0f;
    }
    __syncthreads();
#pragma unroll
    for (int kk = 0; kk < 32; kk++) {
      float4 a0 = *reinterpret_cast<const float4*>(&HT[k0 + kk][r0]);
      float4 a1 = *reinterpret_cast<const float4*>(&HT[k0 + kk][r0 + 4]);
      float b0 = Ws3[kk][c3], b1v = Ws3[kk][c3 + 1], b2v = Ws3[kk][c3 + 2];
      float av[8] = {a0.x, a0.y, a0.z, a0.w, a1.x, a1.y, a1.z, a1.w};
      float bv3[3] = {b0, b1v, b2v};
#pragma unroll
      for (int i = 0; i < 8; i++)
#pragma unroll
        for (int j = 0; j < 3; j++) acc3f[i][j] = fmaf(av[i], bv3[j], acc3f[i][j]);
    }
    if ((k0 & 63) == 32) {
#pragma unroll
      for (int i = 0; i < 8; i++)
#pragma unroll
        for (int j = 0; j < 3; j++) { acc3d[i][j] += (double)acc3f[i][j]; acc3f[i][j] = 0.0f; }
    }
    __syncthreads();
  }
  {
    float b3v[3];
#pragma unroll
    for (int j = 0; j < 3; j++) b3v[j] = (c3 + j < 94) ? b3[c3 + j] : 0.0f;
#pragma unroll
    for (int i = 0; i < 8; i++)
#pragma unroll
      for (int j = 0; j < 3; j++)
        Lsr[r0 + i][c3 + j] = (float)acc3d[i][j] + b3v[j];
  }
#pragma unroll
  for (int i = 0; i < 24; i++) {
    int idx = t + i * 256;
    if (idx < 64 * 94) Amf[idx] = AM[(size_t)rowBase * 94 + idx];
  }
  __syncthreads();

  if (t < 64) {
    const int row = rowBase + t;
    const float NI = -__builtin_huge_valf();
    const int* am = Amf + t * 94;
    int sum0 = 0, sum1 = 0;
    for (int a = 0; a < NACT; a++) { sum0 += am[a]; sum1 += am[NACT + a]; }
    const bool fp1 = (sum0 == 1) && (am[0] == 1);
    const bool fp2 = (sum1 == 1) && (am[NACT] == 1);
    float bestv = NI; int a1s = 0;
    for (int a = 0; a < NACT; a++) {
      float l = (am[a] != 0) ? Lsr[t][a] : NI;
      if (fp2 && !fp1 && a == 0) l = NI;
      float v = l + gumbel_at(K1A, K1B, (u32)row * 47u + (u32)a);
      if (v > bestv) { bestv = v; a1s = a; }
    }
    const int a1 = fp1 ? 0 : a1s;
    const bool sw1 = (a1 >= 1) && (a1 <= 6);
    const bool mv1 = (a1 >= 27) && (a1 <= 46);
    bestv = NI; int a2s = 0;
    for (int a = 0; a < NACT; a++) {
      float l = (am[NACT + a] != 0) ? Lsr[t][NACT + a] : NI;
      bool extra = (sw1 && a == a1) || (mv1 && a >= 27 && a < 46);
      bool m2 = (fp1 && !fp2 && a == 0) || (!fp1 && !fp2 && extra);
      if (m2) l = NI;
      float v = l + gumbel_at(K2A, K2B, (u32)row * 47u + (u32)a);
      if (v > bestv) { bestv = v; a2s = a; }
    }
    const int a2 = fp2 ? 0 : a2s;
    out[(size_t)row * 2 + 0] = a1;
    out[(size_t)row * 2 + 1] = a2;
  }
}

extern "C" void kernel_launch(void* const* d_in, const int* in_sizes, int n_in,
                              void* d_out, int out_size, void* d_ws, size_t ws_size,
                              hipStream_t stream) {
  const float* X  = (const float*)d_in[0];
  const int*   AM = (const int*)d_in[1];
  const float* W1 = (const float*)d_in[2];
  const float* b1 = (const float*)d_in[3];
  const float* W2 = (const float*)d_in[4];
  const float* b2 = (const float*)d_in[5];
  const float* W3 = (const float*)d_in[6];
  const float* b3 = (const float*)d_in[7];
  int* out = (int*)d_out;

  if (ws_size >= (size_t)WS_NEEDED) {
    prep_weights<<<624, 256, 0, stream>>>(W1, W2, W3, (char*)d_ws);
    fused_mfma<<<1024, 256, 0, stream>>>(X, AM, b1, b2, b3, (const char*)d_ws, out);
  } else {
    fused_policy_v1<<<1024, 256, 0, stream>>>(X, AM, W1, b1, W2, b2, W3, b3, out);
  }
}